// Round 14
// baseline (1213.343 us; speedup 1.0000x reference)
//
#include <hip/hip_runtime.h>

#define NN 100000
#define NE 3200000
#define DIN 512
#define DHID 256
#define DOUT 64
#define KPROP 10
#define TSH 13                 // tile shift: 8192 dsts per tile
#define TMSK 8191
#define NT 13                  // 13*8192 = 106496 >= NN
#define NCH 32                 // edge chunks
#define CHSZ (NE / NCH)        // 100000 edges per chunk

typedef _Float16 f16;
typedef _Float16 f16x8 __attribute__((ext_vector_type(8)));
typedef _Float16 f16x4 __attribute__((ext_vector_type(4)));
typedef float f32x4 __attribute__((ext_vector_type(4)));

// ---------------- edge-index layout probe (wave-parallel) ----------------
__global__ void detect_i64(const int* __restrict__ ei, int* __restrict__ flag) {
  int lane = threadIdx.x;
  int ok = 1;
  for (int i = lane; i < 512; i += 64)
    if (ei[2 * i + 1] != 0) ok = 0;
  ok = __all(ok);
  if (lane == 0) *flag = ok;
}

// ---------------- CSR build pass A: tile-LDS counting --------------------
// r12/r13 falsified: 3.2M global returning atomics cost ~142us and 112MB of
// coherence-point write traffic REGARDLESS of locality tricks (routing/NT/
// color-privatization all neutral). Fix: count in LDS (8192-bin tile per
// block, 32KB), zero global atomics; partial counts stored coalesced.
__global__ __launch_bounds__(256) void count_tile(
    const int* __restrict__ ei, const int* __restrict__ flag,
    int* __restrict__ pc /* [NT][NCH][8192] */) {
  int t = blockIdx.x >> 5;
  int c = blockIdx.x & 31;
  __shared__ int lc[8192];
  for (int j = threadIdx.x; j < 8192; j += 256) lc[j] = 0;
  __syncthreads();
  int is64 = *flag;
  const int* dstp = ei + (is64 ? 2 * (size_t)NE : (size_t)NE);
  int st = is64 ? 2 : 1;
  int end = (c + 1) * CHSZ;
  for (int i = c * CHSZ + threadIdx.x; i < end; i += 256) {
    int d = dstp[(size_t)i * st];
    if ((d >> TSH) == t) atomicAdd(&lc[d & TMSK], 1);
  }
  __syncthreads();
  for (int j = threadIdx.x; j < 8192; j += 256)
    pc[((size_t)t * NCH + c) * 8192 + j] = lc[j];
}

// ---------------- pass A2: per-(tile,bin) chunk prefix + total degree -----
__global__ void tile_offsets(int* __restrict__ pc, int* __restrict__ deg) {
  int g = blockIdx.x * 256 + threadIdx.x;   // over NT*8192
  if (g >= NT * 8192) return;
  int t = g >> TSH, j = g & TMSK;
  int run = 0;
  #pragma unroll 4
  for (int c = 0; c < NCH; c++) {
    size_t idx = ((size_t)t * NCH + c) * 8192 + j;
    int v = pc[idx];
    pc[idx] = run;                          // chunk-exclusive offset
    run += v;
  }
  int node = (t << TSH) + j;
  if (node < NN) deg[node] = run;
}

// ---------------- exclusive scan over degree ----------------
__global__ void scan1(const int* __restrict__ deg, int* __restrict__ rs,
                      int* __restrict__ bsum) {
  __shared__ int tmp[1024];
  int t = threadIdx.x;
  int g = blockIdx.x * 1024 + t;
  int v = (g < NN) ? deg[g] : 0;
  tmp[t] = v;
  __syncthreads();
  for (int off = 1; off < 1024; off <<= 1) {
    int y = (t >= off) ? tmp[t - off] : 0;
    __syncthreads();
    tmp[t] += y;
    __syncthreads();
  }
  if (g < NN) rs[g] = tmp[t] - v;           // exclusive
  if (t == 1023) bsum[blockIdx.x] = tmp[t]; // block total
}

__global__ void scan2(int* __restrict__ bsum, int nb) {
  if (blockIdx.x == 0 && threadIdx.x == 0) {
    int s = 0;
    for (int i = 0; i < nb; i++) { int v = bsum[i]; bsum[i] = s; s += v; }
  }
}

__global__ void scan3_and_dis(int* __restrict__ rs, const int* __restrict__ bsum,
                              const int* __restrict__ deg, float* __restrict__ dis) {
  int g = blockIdx.x * blockDim.x + threadIdx.x;
  if (g < NN) {
    rs[g] = rs[g] + bsum[g >> 10];
    dis[g] = rsqrtf((float)(deg[g] + 1)); // +1 self-loop
  }
}

// ---------------- pass B: tile-LDS fill (atomic-free globally) ------------
// LDS cursor = rs[node] + chunk offset; rank via LDS atomicAdd. recs writes
// cluster into the tile's contiguous CSR region (better write locality than
// all-random scatter).
__global__ __launch_bounds__(256) void fill_tile(
    const int* __restrict__ ei, const int* __restrict__ flag,
    const float* __restrict__ dis, const int* __restrict__ rs,
    const int* __restrict__ pc, int2* __restrict__ recs) {
  int t = blockIdx.x >> 5;
  int c = blockIdx.x & 31;
  __shared__ int cur[8192];
  int tb = t << TSH;
  for (int j = threadIdx.x; j < 8192; j += 256) {
    int node = tb + j;
    cur[j] = (node < NN) ? rs[node] + pc[((size_t)t * NCH + c) * 8192 + j] : 0;
  }
  __syncthreads();
  int is64 = *flag;
  const int* srcp = ei;
  const int* dstp = ei + (is64 ? 2 * (size_t)NE : (size_t)NE);
  int st = is64 ? 2 : 1;
  int end = (c + 1) * CHSZ;
  for (int i = c * CHSZ + threadIdx.x; i < end; i += 256) {
    int d = dstp[(size_t)i * st];
    if ((d >> TSH) == t) {
      int s = srcp[(size_t)i * st];
      int p = atomicAdd(&cur[d & TMSK], 1);
      recs[p] = make_int2(s, __float_as_int(dis[s] * dis[d]));
    }
  }
}

// ---------------- weight transpose + fp16 convert ----------------
__global__ void cvt_weights(const float* __restrict__ W1, const float* __restrict__ W2,
                            f16* __restrict__ W1t, f16* __restrict__ W2t) {
  int g = blockIdx.x * 256 + threadIdx.x;
  if (g < DIN * DHID) {
    int k = g >> 8, n = g & 255;
    W1t[(size_t)n * DIN + k] = (f16)W1[g];
  }
  if (g < DHID * DOUT) {
    int k = g >> 6, n = g & 63;
    W2t[(size_t)n * DHID + k] = (f16)W2[g];
  }
}

// ---------------- fused MLP via f16 MFMA (pipelined, union LDS) ----------
__global__ __launch_bounds__(256) void mlp_mfma(
    const float* __restrict__ x, const f16* __restrict__ W1t,
    const float* __restrict__ b1, const f16* __restrict__ W2t,
    const float* __restrict__ b2, const float* __restrict__ temp,
    f16* __restrict__ h, f16* __restrict__ z)
{
  __shared__ __align__(16) char smraw[2 * 64 * 136 * 2]; // 34816 B
  f16* xsb = (f16*)smraw;          // xs[buf][row][136]
  f16* h1s = (f16*)smraw;          // h1s[row][264] (aliases xs; disjoint lifetime)
  int t = threadIdx.x;
  int lane = t & 63;
  int w = t >> 6;
  int n0 = blockIdx.x * 64;
  int r15 = lane & 15;
  int g4 = lane >> 4;
  int nbase = w * 64;
  int srow = t >> 5, sc4 = t & 31;

  f32x4 acc[4][4];
  #pragma unroll
  for (int nt = 0; nt < 4; nt++) {
    float bv = b1[nbase + nt * 16 + r15];
    #pragma unroll
    for (int mt = 0; mt < 4; mt++) acc[mt][nt] = (f32x4){bv, bv, bv, bv};
  }

  float4 ld[8];
  #pragma unroll
  for (int it = 0; it < 8; it++) {
    int row = srow + it * 8;
    int gr = n0 + row;
    ld[it] = (gr < NN) ? *(const float4*)&x[(size_t)gr * DIN + sc4 * 4]
                       : make_float4(0.f, 0.f, 0.f, 0.f);
  }
  #pragma unroll
  for (int it = 0; it < 8; it++) {
    int row = srow + it * 8;
    f16x4 hv = { (f16)ld[it].x, (f16)ld[it].y, (f16)ld[it].z, (f16)ld[it].w };
    *(f16x4*)&xsb[row * 136 + sc4 * 4] = hv;
  }
  __syncthreads();

  for (int c = 0; c < 4; c++) {
    int cur = c & 1;
    if (c < 3) {
      #pragma unroll
      for (int it = 0; it < 8; it++) {
        int row = srow + it * 8;
        int gr = n0 + row;
        ld[it] = (gr < NN)
            ? *(const float4*)&x[(size_t)gr * DIN + (c + 1) * 128 + sc4 * 4]
            : make_float4(0.f, 0.f, 0.f, 0.f);
      }
    }
    int k0 = c * 128;
    const f16* xs = xsb + cur * 8704;
    #pragma unroll
    for (int ks = 0; ks < 4; ks++) {
      int kk = ks * 32 + g4 * 8;
      f16x8 a[4], b[4];
      #pragma unroll
      for (int mt = 0; mt < 4; mt++)
        a[mt] = *(const f16x8*)&xs[(mt * 16 + r15) * 136 + kk];
      #pragma unroll
      for (int nt = 0; nt < 4; nt++)
        b[nt] = *(const f16x8*)&W1t[(size_t)(nbase + nt * 16 + r15) * DIN + k0 + kk];
      #pragma unroll
      for (int mt = 0; mt < 4; mt++)
        #pragma unroll
        for (int nt = 0; nt < 4; nt++)
          acc[mt][nt] = __builtin_amdgcn_mfma_f32_16x16x32_f16(a[mt], b[nt], acc[mt][nt], 0, 0, 0);
    }
    if (c < 3) {
      #pragma unroll
      for (int it = 0; it < 8; it++) {
        int row = srow + it * 8;
        f16x4 hv = { (f16)ld[it].x, (f16)ld[it].y, (f16)ld[it].z, (f16)ld[it].w };
        *(f16x4*)&xsb[(cur ^ 1) * 8704 + row * 136 + sc4 * 4] = hv;
      }
    }
    __syncthreads();
  }

  #pragma unroll
  for (int mt = 0; mt < 4; mt++)
    #pragma unroll
    for (int nt = 0; nt < 4; nt++)
      #pragma unroll
      for (int r = 0; r < 4; r++) {
        float v = fmaxf(acc[mt][nt][r], 0.f);
        h1s[(mt * 16 + g4 * 4 + r) * 264 + nbase + nt * 16 + r15] = (f16)v;
      }
  __syncthreads();

  f32x4 acc2[4];
  #pragma unroll
  for (int nt = 0; nt < 4; nt++) {
    float bv = b2[nt * 16 + r15];
    acc2[nt] = (f32x4){bv, bv, bv, bv};
  }
  #pragma unroll
  for (int ks = 0; ks < 8; ks++) {
    int kk = ks * 32 + g4 * 8;
    f16x8 a2 = *(const f16x8*)&h1s[(w * 16 + r15) * 264 + kk];
    #pragma unroll
    for (int nt = 0; nt < 4; nt++) {
      f16x8 bf = *(const f16x8*)&W2t[(size_t)(nt * 16 + r15) * DHID + kk];
      acc2[nt] = __builtin_amdgcn_mfma_f32_16x16x32_f16(a2, bf, acc2[nt], 0, 0, 0);
    }
  }
  float tK = temp[KPROP];
  #pragma unroll
  for (int nt = 0; nt < 4; nt++)
    #pragma unroll
    for (int r = 0; r < 4; r++) {
      int node = n0 + w * 16 + g4 * 4 + r;
      if (node < NN) {
        int colv = nt * 16 + r15;
        float v = acc2[nt][r];
        h[(size_t)node * DOUT + colv] = (f16)v;
        z[(size_t)node * DOUT + colv] = (f16)(tK * v);
      }
    }
}

// ---------------- Horner propagation: z_new = temp[k]*h + A_hat z ----------
// r8/r12 measured-best form (row-major z, 8 neighbor rows per dwordx4;
// q=lane>>3 edge slot, s8=lane&7 feature octet; butterfly xor 8/16/32).
__global__ __launch_bounds__(256) void prop_horner(
    const f16* __restrict__ z, f16* __restrict__ zn, const f16* __restrict__ h,
    float* __restrict__ out, const int* __restrict__ rs, const int* __restrict__ rs1,
    const int2* __restrict__ recs, const float* __restrict__ dis,
    const float* __restrict__ temp, int kidx, int final_step)
{
  int w = blockIdx.x * 4 + (threadIdx.x >> 6);
  int lane = threadIdx.x & 63;
  if (w >= NN) return;
  int q = lane >> 3;
  int s8 = lane & 7;

  float acc[8];
  #pragma unroll
  for (int f = 0; f < 8; f++) acc[f] = 0.f;

  int beg = rs[w];
  int n = ((w < NN - 1) ? rs1[w] : NE) - beg;
  const int2* rp = recs + beg;

  int e = 0;
  for (; e + 32 <= n; e += 32) {
    int2 r0 = rp[e + q];
    int2 r1 = rp[e + 8 + q];
    int2 r2 = rp[e + 16 + q];
    int2 r3 = rp[e + 24 + q];
    f16x8 g0 = *(const f16x8*)&z[(size_t)r0.x * DOUT + s8 * 8];
    f16x8 g1 = *(const f16x8*)&z[(size_t)r1.x * DOUT + s8 * 8];
    f16x8 g2 = *(const f16x8*)&z[(size_t)r2.x * DOUT + s8 * 8];
    f16x8 g3 = *(const f16x8*)&z[(size_t)r3.x * DOUT + s8 * 8];
    float w0 = __int_as_float(r0.y);
    float w1 = __int_as_float(r1.y);
    float w2 = __int_as_float(r2.y);
    float w3 = __int_as_float(r3.y);
    #pragma unroll
    for (int f = 0; f < 8; f++) acc[f] = fmaf(w0, (float)g0[f], acc[f]);
    #pragma unroll
    for (int f = 0; f < 8; f++) acc[f] = fmaf(w1, (float)g1[f], acc[f]);
    #pragma unroll
    for (int f = 0; f < 8; f++) acc[f] = fmaf(w2, (float)g2[f], acc[f]);
    #pragma unroll
    for (int f = 0; f < 8; f++) acc[f] = fmaf(w3, (float)g3[f], acc[f]);
  }
  for (; e + 8 <= n; e += 8) {
    int2 r0 = rp[e + q];
    f16x8 g0 = *(const f16x8*)&z[(size_t)r0.x * DOUT + s8 * 8];
    float w0 = __int_as_float(r0.y);
    #pragma unroll
    for (int f = 0; f < 8; f++) acc[f] = fmaf(w0, (float)g0[f], acc[f]);
  }
  if (e < n) {
    int rem = n - e;
    int qq = q < rem ? q : rem - 1;   // clamp; invalid slots get weight 0
    int2 r0 = rp[e + qq];
    f16x8 g0 = *(const f16x8*)&z[(size_t)r0.x * DOUT + s8 * 8];
    float w0 = (q < rem) ? __int_as_float(r0.y) : 0.f;
    #pragma unroll
    for (int f = 0; f < 8; f++) acc[f] = fmaf(w0, (float)g0[f], acc[f]);
  }

  #pragma unroll
  for (int f = 0; f < 8; f++) {
    acc[f] += __shfl_xor(acc[f], 8);
    acc[f] += __shfl_xor(acc[f], 16);
    acc[f] += __shfl_xor(acc[f], 32);
  }

  if (q == 0) {
    float dd = dis[w];
    float dd2 = dd * dd;              // self-loop norm
    float gk = temp[kidx];
    f16x8 zs = *(const f16x8*)&z[(size_t)w * DOUT + s8 * 8];
    f16x8 hs = *(const f16x8*)&h[(size_t)w * DOUT + s8 * 8];
    #pragma unroll
    for (int f = 0; f < 8; f++)
      acc[f] += dd2 * (float)zs[f] + gk * (float)hs[f];
    if (final_step) {
      float4 o0 = { acc[0], acc[1], acc[2], acc[3] };
      float4 o1 = { acc[4], acc[5], acc[6], acc[7] };
      *(float4*)&out[(size_t)w * DOUT + s8 * 8] = o0;
      *(float4*)&out[(size_t)w * DOUT + s8 * 8 + 4] = o1;
    } else {
      f16x8 o;
      #pragma unroll
      for (int f = 0; f < 8; f++) o[f] = (f16)acc[f];
      *(f16x8*)&zn[(size_t)w * DOUT + s8 * 8] = o;
    }
  }
}

// ---------------- launch ----------------
extern "C" void kernel_launch(void* const* d_in, const int* in_sizes, int n_in,
                              void* d_out, int out_size, void* d_ws, size_t ws_size,
                              hipStream_t stream) {
  const float* x    = (const float*)d_in[0];
  const int*   ei   = (const int*)d_in[1];
  const float* W1   = (const float*)d_in[2];
  const float* b1   = (const float*)d_in[3];
  const float* W2   = (const float*)d_in[4];
  const float* b2   = (const float*)d_in[5];
  const float* temp = (const float*)d_in[6];
  float* out = (float*)d_out;

  char* wsb = (char*)d_ws;
  size_t off = 0;
  auto carve = [&](size_t bytes) -> void* {
    void* p = wsb + off;
    off = (off + bytes + 255) & ~(size_t)255;
    return p;
  };
  int*   pc     = (int*)carve((size_t)NT * NCH * 8192 * 4); // 13.6 MB
  int*   deg    = (int*)carve((size_t)NN * 4);
  int*   rs     = (int*)carve((size_t)NN * 4);
  int*   bsum   = (int*)carve(128 * 4);
  int*   flag   = (int*)carve(256);
  float* dis    = (float*)carve((size_t)NN * 4);
  int2*  recs   = (int2*)carve((size_t)NE * 8);  // 25.6 MB
  f16*   W1t    = (f16*)carve((size_t)DHID * DIN * 2);
  f16*   W2t    = (f16*)carve((size_t)DOUT * DHID * 2);
  f16*   h_buf  = (f16*)carve((size_t)NN * DOUT * 2);
  f16*   z_a    = (f16*)carve((size_t)NN * DOUT * 2);
  f16*   z_b    = (f16*)carve((size_t)NN * DOUT * 2);
  if (off > ws_size) return; // ~81 MB needed (fits: r13 used 83)

  detect_i64<<<1, 64, 0, stream>>>(ei, flag);
  count_tile<<<NT * NCH, 256, 0, stream>>>(ei, flag, pc);
  tile_offsets<<<(NT * 8192 + 255) / 256, 256, 0, stream>>>(pc, deg);
  scan1<<<(NN + 1023) / 1024, 1024, 0, stream>>>(deg, rs, bsum);
  scan2<<<1, 64, 0, stream>>>(bsum, (NN + 1023) / 1024);
  scan3_and_dis<<<(NN + 255) / 256, 256, 0, stream>>>(rs, bsum, deg, dis);
  fill_tile<<<NT * NCH, 256, 0, stream>>>(ei, flag, dis, rs, pc, recs);

  cvt_weights<<<(DIN * DHID + 255) / 256, 256, 0, stream>>>(W1, W2, W1t, W2t);
  mlp_mfma<<<(NN + 63) / 64, 256, 0, stream>>>(x, W1t, b1, W2t, b2, temp, h_buf, z_a);

  const f16* zc = z_a;
  f16* zn = z_b;
  for (int k = KPROP - 1; k >= 0; k--) {
    prop_horner<<<(NN + 3) / 4, 256, 0, stream>>>(zc, zn, h_buf, out, rs, rs + 1,
                                                  recs, dis, temp, k, k == 0);
    const f16* t2 = zn;
    zn = (f16*)zc;
    zc = t2;
  }
}

// Round 15
// 1027.361 us; speedup vs baseline: 1.1810x; 1.1810x over previous
//
#include <hip/hip_runtime.h>

#define NN 100000
#define NE 3200000
#define DIN 512
#define DHID 256
#define DOUT 64
#define KPROP 10

typedef _Float16 f16;
typedef _Float16 f16x8 __attribute__((ext_vector_type(8)));
typedef _Float16 f16x4 __attribute__((ext_vector_type(4)));
typedef float f32x4 __attribute__((ext_vector_type(4)));

// ---------------- edge-index layout probe (wave-parallel) ----------------
__global__ void detect_i64(const int* __restrict__ ei, int* __restrict__ flag) {
  int lane = threadIdx.x;
  int ok = 1;
  for (int i = lane; i < 512; i += 64)
    if (ei[2 * i + 1] != 0) ok = 0;
  ok = __all(ok);
  if (lane == 0) *flag = ok;
}

__global__ void zero_cnt(int* __restrict__ cnt) {
  int g = blockIdx.x * blockDim.x + threadIdx.x;
  if (g < NN) cnt[g] = 0;
}

// ---------------- degree count + per-edge rank (r12 measured-best) -------
// 3.2M global returning atomics ~147us: r8 routing / r11 NT / r13 coloring /
// r14 tile-LDS all failed to beat it — atomics execute at the memory-side
// coherence point; locality tricks don't apply. This is the measured floor.
__global__ void count_deg(const int* __restrict__ ei, const int* __restrict__ flag,
                          int* __restrict__ cnt, int* __restrict__ rank) {
  int g = blockIdx.x * blockDim.x + threadIdx.x;
  int e0 = g * 4;
  if (e0 >= NE) return;
  int is64 = *flag;
  int d0, d1, d2, d3;
  if (is64) {
    int4 a = *(const int4*)&ei[2 * (size_t)NE + 2 * (size_t)e0];
    int4 b = *(const int4*)&ei[2 * (size_t)NE + 2 * (size_t)e0 + 4];
    d0 = a.x; d1 = a.z; d2 = b.x; d3 = b.z;
  } else {
    int4 a = *(const int4*)&ei[(size_t)NE + e0];
    d0 = a.x; d1 = a.y; d2 = a.z; d3 = a.w;
  }
  int4 rk;
  rk.x = atomicAdd(&cnt[d0], 1);
  rk.y = atomicAdd(&cnt[d1], 1);
  rk.z = atomicAdd(&cnt[d2], 1);
  rk.w = atomicAdd(&cnt[d3], 1);
  *(int4*)&rank[e0] = rk;
}

// ---------------- exclusive scan over cnt ----------------
__global__ void scan1(const int* __restrict__ cnt, int* __restrict__ rs,
                      int* __restrict__ bsum) {
  __shared__ int tmp[1024];
  int t = threadIdx.x;
  int g = blockIdx.x * 1024 + t;
  int v = (g < NN) ? cnt[g] : 0;
  tmp[t] = v;
  __syncthreads();
  for (int off = 1; off < 1024; off <<= 1) {
    int y = (t >= off) ? tmp[t - off] : 0;
    __syncthreads();
    tmp[t] += y;
    __syncthreads();
  }
  if (g < NN) rs[g] = tmp[t] - v;           // exclusive
  if (t == 1023) bsum[blockIdx.x] = tmp[t]; // block total
}

__global__ void scan2(int* __restrict__ bsum, int nb) {
  if (blockIdx.x == 0 && threadIdx.x == 0) {
    int s = 0;
    for (int i = 0; i < nb; i++) { int v = bsum[i]; bsum[i] = s; s += v; }
  }
}

__global__ void scan3_and_dis(int* __restrict__ rs, const int* __restrict__ bsum,
                              const int* __restrict__ cnt, float* __restrict__ dis) {
  int g = blockIdx.x * blockDim.x + threadIdx.x;
  if (g < NN) {
    rs[g] = rs[g] + bsum[g >> 10];
    dis[g] = rsqrtf((float)(cnt[g] + 1)); // +1 self-loop
  }
}

// ---------------- CSR fill: atomic-free via precomputed ranks -------------
__global__ void fill_csr(const int* __restrict__ ei, const int* __restrict__ flag,
                         const float* __restrict__ dis, const int* __restrict__ rs,
                         const int* __restrict__ rank, int2* __restrict__ recs) {
  int g = blockIdx.x * blockDim.x + threadIdx.x;
  int e0 = g * 4;
  if (e0 >= NE) return;
  int is64 = *flag;
  int s[4], d[4];
  if (is64) {
    int4 a = *(const int4*)&ei[2 * (size_t)NE + 2 * (size_t)e0];
    int4 b = *(const int4*)&ei[2 * (size_t)NE + 2 * (size_t)e0 + 4];
    d[0] = a.x; d[1] = a.z; d[2] = b.x; d[3] = b.z;
    int4 c = *(const int4*)&ei[2 * (size_t)e0];
    int4 e = *(const int4*)&ei[2 * (size_t)e0 + 4];
    s[0] = c.x; s[1] = c.z; s[2] = e.x; s[3] = e.z;
  } else {
    int4 a = *(const int4*)&ei[(size_t)NE + e0];
    d[0] = a.x; d[1] = a.y; d[2] = a.z; d[3] = a.w;
    int4 c = *(const int4*)&ei[e0];
    s[0] = c.x; s[1] = c.y; s[2] = c.z; s[3] = c.w;
  }
  int4 rk = *(const int4*)&rank[e0];
  int rka[4] = { rk.x, rk.y, rk.z, rk.w };
  #pragma unroll
  for (int j = 0; j < 4; j++) {
    int pos = rs[d[j]] + rka[j];
    recs[pos] = make_int2(s[j], __float_as_int(dis[s[j]] * dis[d[j]]));
  }
}

// ---------------- weight transpose + fp16 convert ----------------
__global__ void cvt_weights(const float* __restrict__ W1, const float* __restrict__ W2,
                            f16* __restrict__ W1t, f16* __restrict__ W2t) {
  int g = blockIdx.x * 256 + threadIdx.x;
  if (g < DIN * DHID) {
    int k = g >> 8, n = g & 255;
    W1t[(size_t)n * DIN + k] = (f16)W1[g];
  }
  if (g < DHID * DOUT) {
    int k = g >> 6, n = g & 63;
    W2t[(size_t)n * DHID + k] = (f16)W2[g];
  }
}

// ---------------- fused MLP via f16 MFMA (32-row tiles for occupancy) ----
// r13 counters: 64-row version = 141us, Occupancy 19.5%, all pipes <10% ->
// latency-bound, LDS (34.8KB) capped 4 blocks/CU. 32-row tile: LDS 17.4KB ->
// VGPR-capped ~5 blocks/CU, 2x block count (3125) for dispatch smoothing.
__global__ __launch_bounds__(256) void mlp_mfma(
    const float* __restrict__ x, const f16* __restrict__ W1t,
    const float* __restrict__ b1, const f16* __restrict__ W2t,
    const float* __restrict__ b2, const float* __restrict__ temp,
    f16* __restrict__ h, f16* __restrict__ z)
{
  __shared__ __align__(16) char smraw[2 * 32 * 136 * 2]; // 17408 B
  f16* xsb = (f16*)smraw;          // xs[buf][row][136], buf stride 4352
  f16* h1s = (f16*)smraw;          // h1s[row][264] = 16896B (aliased; disjoint lifetime)
  int t = threadIdx.x;
  int lane = t & 63;
  int w = t >> 6;
  int n0 = blockIdx.x * 32;
  int r15 = lane & 15;
  int g4 = lane >> 4;
  int nbase = w * 64;
  int srow = t >> 5, sc4 = t & 31;   // staging: 32 rows x 32 float4, 4/thread

  f32x4 acc[2][4];
  #pragma unroll
  for (int nt = 0; nt < 4; nt++) {
    float bv = b1[nbase + nt * 16 + r15];
    #pragma unroll
    for (int mt = 0; mt < 2; mt++) acc[mt][nt] = (f32x4){bv, bv, bv, bv};
  }

  float4 ld[4];
  #pragma unroll
  for (int it = 0; it < 4; it++) {
    int row = srow + it * 8;
    int gr = n0 + row;
    ld[it] = (gr < NN) ? *(const float4*)&x[(size_t)gr * DIN + sc4 * 4]
                       : make_float4(0.f, 0.f, 0.f, 0.f);
  }
  #pragma unroll
  for (int it = 0; it < 4; it++) {
    int row = srow + it * 8;
    f16x4 hv = { (f16)ld[it].x, (f16)ld[it].y, (f16)ld[it].z, (f16)ld[it].w };
    *(f16x4*)&xsb[row * 136 + sc4 * 4] = hv;
  }
  __syncthreads();

  for (int c = 0; c < 4; c++) {
    int cur = c & 1;
    if (c < 3) {  // prefetch next chunk (latency hides under compute)
      #pragma unroll
      for (int it = 0; it < 4; it++) {
        int row = srow + it * 8;
        int gr = n0 + row;
        ld[it] = (gr < NN)
            ? *(const float4*)&x[(size_t)gr * DIN + (c + 1) * 128 + sc4 * 4]
            : make_float4(0.f, 0.f, 0.f, 0.f);
      }
    }
    int k0 = c * 128;
    const f16* xs = xsb + cur * 4352;
    #pragma unroll
    for (int ks = 0; ks < 4; ks++) {
      int kk = ks * 32 + g4 * 8;
      f16x8 a[2], b[4];
      #pragma unroll
      for (int mt = 0; mt < 2; mt++)
        a[mt] = *(const f16x8*)&xs[(mt * 16 + r15) * 136 + kk];
      #pragma unroll
      for (int nt = 0; nt < 4; nt++)
        b[nt] = *(const f16x8*)&W1t[(size_t)(nbase + nt * 16 + r15) * DIN + k0 + kk];
      #pragma unroll
      for (int mt = 0; mt < 2; mt++)
        #pragma unroll
        for (int nt = 0; nt < 4; nt++)
          acc[mt][nt] = __builtin_amdgcn_mfma_f32_16x16x32_f16(a[mt], b[nt], acc[mt][nt], 0, 0, 0);
    }
    if (c < 3) {
      #pragma unroll
      for (int it = 0; it < 4; it++) {
        int row = srow + it * 8;
        f16x4 hv = { (f16)ld[it].x, (f16)ld[it].y, (f16)ld[it].z, (f16)ld[it].w };
        *(f16x4*)&xsb[(cur ^ 1) * 4352 + row * 136 + sc4 * 4] = hv;
      }
    }
    __syncthreads();
  }

  // relu -> h1s (D layout: col = lane&15, row = g4*4+reg [m89-verified])
  #pragma unroll
  for (int mt = 0; mt < 2; mt++)
    #pragma unroll
    for (int nt = 0; nt < 4; nt++)
      #pragma unroll
      for (int r = 0; r < 4; r++) {
        float v = fmaxf(acc[mt][nt][r], 0.f);
        h1s[(mt * 16 + g4 * 4 + r) * 264 + nbase + nt * 16 + r15] = (f16)v;
      }
  __syncthreads();

  // GEMM2: wave w -> row-tile rt = w&1 (16 rows), col-pair cp = w>>1 (32 cols)
  int rt = w & 1, cp = w >> 1;
  f32x4 acc2[2];
  #pragma unroll
  for (int i = 0; i < 2; i++) {
    float bv = b2[cp * 32 + i * 16 + r15];
    acc2[i] = (f32x4){bv, bv, bv, bv};
  }
  #pragma unroll
  for (int ks = 0; ks < 8; ks++) {
    int kk = ks * 32 + g4 * 8;
    f16x8 a2 = *(const f16x8*)&h1s[(rt * 16 + r15) * 264 + kk];
    #pragma unroll
    for (int i = 0; i < 2; i++) {
      f16x8 bf = *(const f16x8*)&W2t[(size_t)(cp * 32 + i * 16 + r15) * DHID + kk];
      acc2[i] = __builtin_amdgcn_mfma_f32_16x16x32_f16(a2, bf, acc2[i], 0, 0, 0);
    }
  }
  float tK = temp[KPROP];
  #pragma unroll
  for (int i = 0; i < 2; i++)
    #pragma unroll
    for (int r = 0; r < 4; r++) {
      int node = n0 + rt * 16 + g4 * 4 + r;
      if (node < NN) {
        int colv = cp * 32 + i * 16 + r15;
        float v = acc2[i][r];
        h[(size_t)node * DOUT + colv] = (f16)v;
        z[(size_t)node * DOUT + colv] = (f16)(tK * v);
      }
    }
}

// ---------------- Horner propagation: z_new = temp[k]*h + A_hat z ----------
// r8/r12 measured-best form. Self-loop z-row, h-row, dis, temp hoisted to
// the top (issued before the edge loop, consumed after the butterfly) to
// remove the dependent-load tail.
__global__ __launch_bounds__(256) void prop_horner(
    const f16* __restrict__ z, f16* __restrict__ zn, const f16* __restrict__ h,
    float* __restrict__ out, const int* __restrict__ rs, const int* __restrict__ cnt,
    const int2* __restrict__ recs, const float* __restrict__ dis,
    const float* __restrict__ temp, int kidx, int final_step)
{
  int w = blockIdx.x * 4 + (threadIdx.x >> 6);
  int lane = threadIdx.x & 63;
  if (w >= NN) return;
  int q = lane >> 3;
  int s8 = lane & 7;

  // hoisted tail loads (same cache lines for all q -> no extra traffic)
  float dd = dis[w];
  float gk = temp[kidx];
  f16x8 zs = *(const f16x8*)&z[(size_t)w * DOUT + s8 * 8];
  f16x8 hs = *(const f16x8*)&h[(size_t)w * DOUT + s8 * 8];

  float acc[8];
  #pragma unroll
  for (int f = 0; f < 8; f++) acc[f] = 0.f;

  int beg = rs[w], n = cnt[w];
  const int2* rp = recs + beg;

  int e = 0;
  for (; e + 32 <= n; e += 32) {
    int2 r0 = rp[e + q];
    int2 r1 = rp[e + 8 + q];
    int2 r2 = rp[e + 16 + q];
    int2 r3 = rp[e + 24 + q];
    f16x8 g0 = *(const f16x8*)&z[(size_t)r0.x * DOUT + s8 * 8];
    f16x8 g1 = *(const f16x8*)&z[(size_t)r1.x * DOUT + s8 * 8];
    f16x8 g2 = *(const f16x8*)&z[(size_t)r2.x * DOUT + s8 * 8];
    f16x8 g3 = *(const f16x8*)&z[(size_t)r3.x * DOUT + s8 * 8];
    float w0 = __int_as_float(r0.y);
    float w1 = __int_as_float(r1.y);
    float w2 = __int_as_float(r2.y);
    float w3 = __int_as_float(r3.y);
    #pragma unroll
    for (int f = 0; f < 8; f++) acc[f] = fmaf(w0, (float)g0[f], acc[f]);
    #pragma unroll
    for (int f = 0; f < 8; f++) acc[f] = fmaf(w1, (float)g1[f], acc[f]);
    #pragma unroll
    for (int f = 0; f < 8; f++) acc[f] = fmaf(w2, (float)g2[f], acc[f]);
    #pragma unroll
    for (int f = 0; f < 8; f++) acc[f] = fmaf(w3, (float)g3[f], acc[f]);
  }
  for (; e + 8 <= n; e += 8) {
    int2 r0 = rp[e + q];
    f16x8 g0 = *(const f16x8*)&z[(size_t)r0.x * DOUT + s8 * 8];
    float w0 = __int_as_float(r0.y);
    #pragma unroll
    for (int f = 0; f < 8; f++) acc[f] = fmaf(w0, (float)g0[f], acc[f]);
  }
  if (e < n) {
    int rem = n - e;
    int qq = q < rem ? q : rem - 1;   // clamp; invalid slots get weight 0
    int2 r0 = rp[e + qq];
    f16x8 g0 = *(const f16x8*)&z[(size_t)r0.x * DOUT + s8 * 8];
    float w0 = (q < rem) ? __int_as_float(r0.y) : 0.f;
    #pragma unroll
    for (int f = 0; f < 8; f++) acc[f] = fmaf(w0, (float)g0[f], acc[f]);
  }

  #pragma unroll
  for (int f = 0; f < 8; f++) {
    acc[f] += __shfl_xor(acc[f], 8);
    acc[f] += __shfl_xor(acc[f], 16);
    acc[f] += __shfl_xor(acc[f], 32);
  }

  if (q == 0) {
    float dd2 = dd * dd;              // self-loop norm
    #pragma unroll
    for (int f = 0; f < 8; f++)
      acc[f] += dd2 * (float)zs[f] + gk * (float)hs[f];
    if (final_step) {
      float4 o0 = { acc[0], acc[1], acc[2], acc[3] };
      float4 o1 = { acc[4], acc[5], acc[6], acc[7] };
      *(float4*)&out[(size_t)w * DOUT + s8 * 8] = o0;
      *(float4*)&out[(size_t)w * DOUT + s8 * 8 + 4] = o1;
    } else {
      f16x8 o;
      #pragma unroll
      for (int f = 0; f < 8; f++) o[f] = (f16)acc[f];
      *(f16x8*)&zn[(size_t)w * DOUT + s8 * 8] = o;
    }
  }
}

// ---------------- launch ----------------
extern "C" void kernel_launch(void* const* d_in, const int* in_sizes, int n_in,
                              void* d_out, int out_size, void* d_ws, size_t ws_size,
                              hipStream_t stream) {
  const float* x    = (const float*)d_in[0];
  const int*   ei   = (const int*)d_in[1];
  const float* W1   = (const float*)d_in[2];
  const float* b1   = (const float*)d_in[3];
  const float* W2   = (const float*)d_in[4];
  const float* b2   = (const float*)d_in[5];
  const float* temp = (const float*)d_in[6];
  float* out = (float*)d_out;

  char* wsb = (char*)d_ws;
  size_t off = 0;
  auto carve = [&](size_t bytes) -> void* {
    void* p = wsb + off;
    off = (off + bytes + 255) & ~(size_t)255;
    return p;
  };
  int*   cnt    = (int*)carve((size_t)NN * 4);
  int*   rs     = (int*)carve((size_t)NN * 4);
  int*   bsum   = (int*)carve(128 * 4);
  int*   flag   = (int*)carve(256);
  float* dis    = (float*)carve((size_t)NN * 4);
  int*   rank   = (int*)carve((size_t)NE * 4);   // 12.8 MB
  int2*  recs   = (int2*)carve((size_t)NE * 8);  // 25.6 MB
  f16*   W1t    = (f16*)carve((size_t)DHID * DIN * 2);
  f16*   W2t    = (f16*)carve((size_t)DOUT * DHID * 2);
  f16*   h_buf  = (f16*)carve((size_t)NN * DOUT * 2);
  f16*   z_a    = (f16*)carve((size_t)NN * DOUT * 2);
  f16*   z_b    = (f16*)carve((size_t)NN * DOUT * 2);
  if (off > ws_size) return; // ~80 MB needed

  detect_i64<<<1, 64, 0, stream>>>(ei, flag);
  zero_cnt<<<(NN + 255) / 256, 256, 0, stream>>>(cnt);
  count_deg<<<(NE / 4 + 255) / 256, 256, 0, stream>>>(ei, flag, cnt, rank);
  scan1<<<(NN + 1023) / 1024, 1024, 0, stream>>>(cnt, rs, bsum);
  scan2<<<1, 64, 0, stream>>>(bsum, (NN + 1023) / 1024);
  scan3_and_dis<<<(NN + 255) / 256, 256, 0, stream>>>(rs, bsum, cnt, dis);
  fill_csr<<<(NE / 4 + 255) / 256, 256, 0, stream>>>(ei, flag, dis, rs, rank, recs);

  cvt_weights<<<(DIN * DHID + 255) / 256, 256, 0, stream>>>(W1, W2, W1t, W2t);
  mlp_mfma<<<(NN + 31) / 32, 256, 0, stream>>>(x, W1t, b1, W2t, b2, temp, h_buf, z_a);

  const f16* zc = z_a;
  f16* zn = z_b;
  for (int k = KPROP - 1; k >= 0; k--) {
    prop_horner<<<(NN + 3) / 4, 256, 0, stream>>>(zc, zn, h_buf, out, rs, cnt,
                                                  recs, dis, temp, k, k == 0);
    const f16* t2 = zn;
    zn = (f16*)zc;
    zc = t2;
  }
}

// Round 16
// 1003.531 us; speedup vs baseline: 1.2091x; 1.0237x over previous
//
#include <hip/hip_runtime.h>

#define NN 100000
#define NE 3200000
#define DIN 512
#define DHID 256
#define DOUT 64
#define KPROP 10

typedef _Float16 f16;
typedef _Float16 f16x8 __attribute__((ext_vector_type(8)));
typedef _Float16 f16x4 __attribute__((ext_vector_type(4)));
typedef float f32x4 __attribute__((ext_vector_type(4)));

// ---------------- edge-index layout probe (wave-parallel) ----------------
__global__ void detect_i64(const int* __restrict__ ei, int* __restrict__ flag) {
  int lane = threadIdx.x;
  int ok = 1;
  for (int i = lane; i < 512; i += 64)
    if (ei[2 * i + 1] != 0) ok = 0;
  ok = __all(ok);
  if (lane == 0) *flag = ok;
}

__global__ void zero_cnt(int* __restrict__ cnt) {
  int g = blockIdx.x * blockDim.x + threadIdx.x;
  if (g < NN) cnt[g] = 0;
}

// ---------------- degree count + per-edge rank (r12 measured-best) -------
// 3.2M global returning atomics ~147us: r8 routing / r11 NT / r13 coloring /
// r14 tile-LDS all failed to beat it — atomics execute at the memory-side
// coherence point; locality tricks don't apply. Measured floor.
__global__ void count_deg(const int* __restrict__ ei, const int* __restrict__ flag,
                          int* __restrict__ cnt, int* __restrict__ rank) {
  int g = blockIdx.x * blockDim.x + threadIdx.x;
  int e0 = g * 4;
  if (e0 >= NE) return;
  int is64 = *flag;
  int d0, d1, d2, d3;
  if (is64) {
    int4 a = *(const int4*)&ei[2 * (size_t)NE + 2 * (size_t)e0];
    int4 b = *(const int4*)&ei[2 * (size_t)NE + 2 * (size_t)e0 + 4];
    d0 = a.x; d1 = a.z; d2 = b.x; d3 = b.z;
  } else {
    int4 a = *(const int4*)&ei[(size_t)NE + e0];
    d0 = a.x; d1 = a.y; d2 = a.z; d3 = a.w;
  }
  int4 rk;
  rk.x = atomicAdd(&cnt[d0], 1);
  rk.y = atomicAdd(&cnt[d1], 1);
  rk.z = atomicAdd(&cnt[d2], 1);
  rk.w = atomicAdd(&cnt[d3], 1);
  *(int4*)&rank[e0] = rk;
}

// ---------------- exclusive scan over cnt ----------------
__global__ void scan1(const int* __restrict__ cnt, int* __restrict__ rs,
                      int* __restrict__ bsum) {
  __shared__ int tmp[1024];
  int t = threadIdx.x;
  int g = blockIdx.x * 1024 + t;
  int v = (g < NN) ? cnt[g] : 0;
  tmp[t] = v;
  __syncthreads();
  for (int off = 1; off < 1024; off <<= 1) {
    int y = (t >= off) ? tmp[t - off] : 0;
    __syncthreads();
    tmp[t] += y;
    __syncthreads();
  }
  if (g < NN) rs[g] = tmp[t] - v;           // exclusive
  if (t == 1023) bsum[blockIdx.x] = tmp[t]; // block total
}

__global__ void scan2(int* __restrict__ bsum, int nb) {
  if (blockIdx.x == 0 && threadIdx.x == 0) {
    int s = 0;
    for (int i = 0; i < nb; i++) { int v = bsum[i]; bsum[i] = s; s += v; }
  }
}

__global__ void scan3_and_dis(int* __restrict__ rs, const int* __restrict__ bsum,
                              const int* __restrict__ cnt, float* __restrict__ dis) {
  int g = blockIdx.x * blockDim.x + threadIdx.x;
  if (g < NN) {
    rs[g] = rs[g] + bsum[g >> 10];
    dis[g] = rsqrtf((float)(cnt[g] + 1)); // +1 self-loop
  }
}

// ---------------- CSR fill: atomic-free via precomputed ranks -------------
__global__ void fill_csr(const int* __restrict__ ei, const int* __restrict__ flag,
                         const float* __restrict__ dis, const int* __restrict__ rs,
                         const int* __restrict__ rank, int2* __restrict__ recs) {
  int g = blockIdx.x * blockDim.x + threadIdx.x;
  int e0 = g * 4;
  if (e0 >= NE) return;
  int is64 = *flag;
  int s[4], d[4];
  if (is64) {
    int4 a = *(const int4*)&ei[2 * (size_t)NE + 2 * (size_t)e0];
    int4 b = *(const int4*)&ei[2 * (size_t)NE + 2 * (size_t)e0 + 4];
    d[0] = a.x; d[1] = a.z; d[2] = b.x; d[3] = b.z;
    int4 c = *(const int4*)&ei[2 * (size_t)e0];
    int4 e = *(const int4*)&ei[2 * (size_t)e0 + 4];
    s[0] = c.x; s[1] = c.z; s[2] = e.x; s[3] = e.z;
  } else {
    int4 a = *(const int4*)&ei[(size_t)NE + e0];
    d[0] = a.x; d[1] = a.y; d[2] = a.z; d[3] = a.w;
    int4 c = *(const int4*)&ei[e0];
    s[0] = c.x; s[1] = c.y; s[2] = c.z; s[3] = c.w;
  }
  int4 rk = *(const int4*)&rank[e0];
  int rka[4] = { rk.x, rk.y, rk.z, rk.w };
  #pragma unroll
  for (int j = 0; j < 4; j++) {
    int pos = rs[d[j]] + rka[j];
    recs[pos] = make_int2(s[j], __float_as_int(dis[s[j]] * dis[d[j]]));
  }
}

// ---------------- weight packing: fragment-major f16 ----------------
// r15 diagnosis: per-lane scattered B-fragment loads (16B/lane from rows 1KB
// apart) occupy the CU memory unit for ~64 lines per wave-load — mlp was
// issue-rate-bound (all pipes <10%). Pack weights so each fragment load is
// one contiguous, coalesced 1KB wave-load:
// W1p[g]*8, g = (((w*4+c)*4+ks)*4+nt)*64+lane: row n=w*64+nt*16+(lane&15),
// cols k = c*128+ks*32+(lane>>4)*8 .. +7 of W1t (= W1[k][n]).
__global__ void cvt_w1(const float* __restrict__ W1, f16* __restrict__ W1p) {
  int g = blockIdx.x * 256 + threadIdx.x;   // 0..16383
  if (g >= 16384) return;
  int lane = g & 63;
  int rest = g >> 6;
  int nt = rest & 3; rest >>= 2;
  int ks = rest & 3; rest >>= 2;
  int c  = rest & 3; rest >>= 2;
  int w  = rest;
  int n = w * 64 + nt * 16 + (lane & 15);
  int kb = c * 128 + ks * 32 + (lane >> 4) * 8;
  f16x8 v;
  #pragma unroll
  for (int j = 0; j < 8; j++) v[j] = (f16)W1[(size_t)(kb + j) * DHID + n];
  *(f16x8*)&W1p[(size_t)g * 8] = v;
}

// W2p[g]*8, g = (ks*4+nt)*64+lane: n = nt*16+(lane&15), k = ks*32+(lane>>4)*8.
__global__ void cvt_w2(const float* __restrict__ W2, f16* __restrict__ W2p) {
  int g = blockIdx.x * 256 + threadIdx.x;   // 0..2047
  if (g >= 2048) return;
  int lane = g & 63;
  int rest = g >> 6;
  int nt = rest & 3;
  int ks = rest >> 2;
  int n = nt * 16 + (lane & 15);
  int kb = ks * 32 + (lane >> 4) * 8;
  f16x8 v;
  #pragma unroll
  for (int j = 0; j < 8; j++) v[j] = (f16)W2[(size_t)(kb + j) * DOUT + n];
  *(f16x8*)&W2p[(size_t)g * 8] = v;
}

// ---------------- fused MLP via f16 MFMA (64-row r13 shape, packed B) ----
__global__ __launch_bounds__(256) void mlp_mfma(
    const float* __restrict__ x, const f16* __restrict__ W1p,
    const float* __restrict__ b1, const f16* __restrict__ W2p,
    const float* __restrict__ b2, const float* __restrict__ temp,
    f16* __restrict__ h, f16* __restrict__ z)
{
  __shared__ __align__(16) char smraw[2 * 64 * 136 * 2]; // 34816 B
  f16* xsb = (f16*)smraw;          // xs[buf][row][136]
  f16* h1s = (f16*)smraw;          // h1s[row][264] (aliased; disjoint lifetime)
  int t = threadIdx.x;
  int lane = t & 63;
  int w = t >> 6;
  int n0 = blockIdx.x * 64;
  int r15 = lane & 15;
  int g4 = lane >> 4;
  int nbase = w * 64;
  int srow = t >> 5, sc4 = t & 31;

  f32x4 acc[4][4];
  #pragma unroll
  for (int nt = 0; nt < 4; nt++) {
    float bv = b1[nbase + nt * 16 + r15];
    #pragma unroll
    for (int mt = 0; mt < 4; mt++) acc[mt][nt] = (f32x4){bv, bv, bv, bv};
  }

  float4 ld[8];
  #pragma unroll
  for (int it = 0; it < 8; it++) {
    int row = srow + it * 8;
    int gr = n0 + row;
    ld[it] = (gr < NN) ? *(const float4*)&x[(size_t)gr * DIN + sc4 * 4]
                       : make_float4(0.f, 0.f, 0.f, 0.f);
  }
  #pragma unroll
  for (int it = 0; it < 8; it++) {
    int row = srow + it * 8;
    f16x4 hv = { (f16)ld[it].x, (f16)ld[it].y, (f16)ld[it].z, (f16)ld[it].w };
    *(f16x4*)&xsb[row * 136 + sc4 * 4] = hv;
  }
  __syncthreads();

  for (int c = 0; c < 4; c++) {
    int cur = c & 1;
    if (c < 3) {  // prefetch next chunk (latency hides under compute)
      #pragma unroll
      for (int it = 0; it < 8; it++) {
        int row = srow + it * 8;
        int gr = n0 + row;
        ld[it] = (gr < NN)
            ? *(const float4*)&x[(size_t)gr * DIN + (c + 1) * 128 + sc4 * 4]
            : make_float4(0.f, 0.f, 0.f, 0.f);
      }
    }
    const f16* xs = xsb + cur * 8704;
    // packed fragment base for (w, c): stride per ks = 4*64*8, per nt = 64*8
    const f16* wp = W1p + ((size_t)(w * 4 + c) * 16 * 64 + lane) * 8;
    #pragma unroll
    for (int ks = 0; ks < 4; ks++) {
      int kk = ks * 32 + g4 * 8;
      f16x8 a[4], b[4];
      #pragma unroll
      for (int mt = 0; mt < 4; mt++)
        a[mt] = *(const f16x8*)&xs[(mt * 16 + r15) * 136 + kk];
      #pragma unroll
      for (int nt = 0; nt < 4; nt++)
        b[nt] = *(const f16x8*)&wp[(size_t)(ks * 4 + nt) * 512];
      #pragma unroll
      for (int mt = 0; mt < 4; mt++)
        #pragma unroll
        for (int nt = 0; nt < 4; nt++)
          acc[mt][nt] = __builtin_amdgcn_mfma_f32_16x16x32_f16(a[mt], b[nt], acc[mt][nt], 0, 0, 0);
    }
    if (c < 3) {
      #pragma unroll
      for (int it = 0; it < 8; it++) {
        int row = srow + it * 8;
        f16x4 hv = { (f16)ld[it].x, (f16)ld[it].y, (f16)ld[it].z, (f16)ld[it].w };
        *(f16x4*)&xsb[(cur ^ 1) * 8704 + row * 136 + sc4 * 4] = hv;
      }
    }
    __syncthreads();
  }

  // relu -> h1s (D layout: col = lane&15, row = g4*4+reg [m89-verified])
  #pragma unroll
  for (int mt = 0; mt < 4; mt++)
    #pragma unroll
    for (int nt = 0; nt < 4; nt++)
      #pragma unroll
      for (int r = 0; r < 4; r++) {
        float v = fmaxf(acc[mt][nt][r], 0.f);
        h1s[(mt * 16 + g4 * 4 + r) * 264 + nbase + nt * 16 + r15] = (f16)v;
      }
  __syncthreads();

  // GEMM2: wave w -> rows w*16..w*16+15, cols 0..63 (packed W2p fragments)
  f32x4 acc2[4];
  #pragma unroll
  for (int nt = 0; nt < 4; nt++) {
    float bv = b2[nt * 16 + r15];
    acc2[nt] = (f32x4){bv, bv, bv, bv};
  }
  const f16* wp2 = W2p + (size_t)lane * 8;
  #pragma unroll
  for (int ks = 0; ks < 8; ks++) {
    int kk = ks * 32 + g4 * 8;
    f16x8 a2 = *(const f16x8*)&h1s[(w * 16 + r15) * 264 + kk];
    #pragma unroll
    for (int nt = 0; nt < 4; nt++) {
      f16x8 bf = *(const f16x8*)&wp2[(size_t)(ks * 4 + nt) * 512];
      acc2[nt] = __builtin_amdgcn_mfma_f32_16x16x32_f16(a2, bf, acc2[nt], 0, 0, 0);
    }
  }
  float tK = temp[KPROP];
  #pragma unroll
  for (int nt = 0; nt < 4; nt++)
    #pragma unroll
    for (int r = 0; r < 4; r++) {
      int node = n0 + w * 16 + g4 * 4 + r;
      if (node < NN) {
        int colv = nt * 16 + r15;
        float v = acc2[nt][r];
        h[(size_t)node * DOUT + colv] = (f16)v;
        z[(size_t)node * DOUT + colv] = (f16)(tK * v);
      }
    }
}

// ---------------- Horner propagation: z_new = temp[k]*h + A_hat z ----------
// r8/r12 measured-best form; self-loop loads hoisted.
__global__ __launch_bounds__(256) void prop_horner(
    const f16* __restrict__ z, f16* __restrict__ zn, const f16* __restrict__ h,
    float* __restrict__ out, const int* __restrict__ rs, const int* __restrict__ cnt,
    const int2* __restrict__ recs, const float* __restrict__ dis,
    const float* __restrict__ temp, int kidx, int final_step)
{
  int w = blockIdx.x * 4 + (threadIdx.x >> 6);
  int lane = threadIdx.x & 63;
  if (w >= NN) return;
  int q = lane >> 3;
  int s8 = lane & 7;

  float dd = dis[w];
  float gk = temp[kidx];
  f16x8 zs = *(const f16x8*)&z[(size_t)w * DOUT + s8 * 8];
  f16x8 hs = *(const f16x8*)&h[(size_t)w * DOUT + s8 * 8];

  float acc[8];
  #pragma unroll
  for (int f = 0; f < 8; f++) acc[f] = 0.f;

  int beg = rs[w], n = cnt[w];
  const int2* rp = recs + beg;

  int e = 0;
  for (; e + 32 <= n; e += 32) {
    int2 r0 = rp[e + q];
    int2 r1 = rp[e + 8 + q];
    int2 r2 = rp[e + 16 + q];
    int2 r3 = rp[e + 24 + q];
    f16x8 g0 = *(const f16x8*)&z[(size_t)r0.x * DOUT + s8 * 8];
    f16x8 g1 = *(const f16x8*)&z[(size_t)r1.x * DOUT + s8 * 8];
    f16x8 g2 = *(const f16x8*)&z[(size_t)r2.x * DOUT + s8 * 8];
    f16x8 g3 = *(const f16x8*)&z[(size_t)r3.x * DOUT + s8 * 8];
    float w0 = __int_as_float(r0.y);
    float w1 = __int_as_float(r1.y);
    float w2 = __int_as_float(r2.y);
    float w3 = __int_as_float(r3.y);
    #pragma unroll
    for (int f = 0; f < 8; f++) acc[f] = fmaf(w0, (float)g0[f], acc[f]);
    #pragma unroll
    for (int f = 0; f < 8; f++) acc[f] = fmaf(w1, (float)g1[f], acc[f]);
    #pragma unroll
    for (int f = 0; f < 8; f++) acc[f] = fmaf(w2, (float)g2[f], acc[f]);
    #pragma unroll
    for (int f = 0; f < 8; f++) acc[f] = fmaf(w3, (float)g3[f], acc[f]);
  }
  for (; e + 8 <= n; e += 8) {
    int2 r0 = rp[e + q];
    f16x8 g0 = *(const f16x8*)&z[(size_t)r0.x * DOUT + s8 * 8];
    float w0 = __int_as_float(r0.y);
    #pragma unroll
    for (int f = 0; f < 8; f++) acc[f] = fmaf(w0, (float)g0[f], acc[f]);
  }
  if (e < n) {
    int rem = n - e;
    int qq = q < rem ? q : rem - 1;   // clamp; invalid slots get weight 0
    int2 r0 = rp[e + qq];
    f16x8 g0 = *(const f16x8*)&z[(size_t)r0.x * DOUT + s8 * 8];
    float w0 = (q < rem) ? __int_as_float(r0.y) : 0.f;
    #pragma unroll
    for (int f = 0; f < 8; f++) acc[f] = fmaf(w0, (float)g0[f], acc[f]);
  }

  #pragma unroll
  for (int f = 0; f < 8; f++) {
    acc[f] += __shfl_xor(acc[f], 8);
    acc[f] += __shfl_xor(acc[f], 16);
    acc[f] += __shfl_xor(acc[f], 32);
  }

  if (q == 0) {
    float dd2 = dd * dd;              // self-loop norm
    #pragma unroll
    for (int f = 0; f < 8; f++)
      acc[f] += dd2 * (float)zs[f] + gk * (float)hs[f];
    if (final_step) {
      float4 o0 = { acc[0], acc[1], acc[2], acc[3] };
      float4 o1 = { acc[4], acc[5], acc[6], acc[7] };
      *(float4*)&out[(size_t)w * DOUT + s8 * 8] = o0;
      *(float4*)&out[(size_t)w * DOUT + s8 * 8 + 4] = o1;
    } else {
      f16x8 o;
      #pragma unroll
      for (int f = 0; f < 8; f++) o[f] = (f16)acc[f];
      *(f16x8*)&zn[(size_t)w * DOUT + s8 * 8] = o;
    }
  }
}

// ---------------- launch ----------------
extern "C" void kernel_launch(void* const* d_in, const int* in_sizes, int n_in,
                              void* d_out, int out_size, void* d_ws, size_t ws_size,
                              hipStream_t stream) {
  const float* x    = (const float*)d_in[0];
  const int*   ei   = (const int*)d_in[1];
  const float* W1   = (const float*)d_in[2];
  const float* b1   = (const float*)d_in[3];
  const float* W2   = (const float*)d_in[4];
  const float* b2   = (const float*)d_in[5];
  const float* temp = (const float*)d_in[6];
  float* out = (float*)d_out;

  char* wsb = (char*)d_ws;
  size_t off = 0;
  auto carve = [&](size_t bytes) -> void* {
    void* p = wsb + off;
    off = (off + bytes + 255) & ~(size_t)255;
    return p;
  };
  int*   cnt    = (int*)carve((size_t)NN * 4);
  int*   rs     = (int*)carve((size_t)NN * 4);
  int*   bsum   = (int*)carve(128 * 4);
  int*   flag   = (int*)carve(256);
  float* dis    = (float*)carve((size_t)NN * 4);
  int*   rank   = (int*)carve((size_t)NE * 4);   // 12.8 MB
  int2*  recs   = (int2*)carve((size_t)NE * 8);  // 25.6 MB
  f16*   W1p    = (f16*)carve((size_t)DHID * DIN * 2);
  f16*   W2p    = (f16*)carve((size_t)DOUT * DHID * 2);
  f16*   h_buf  = (f16*)carve((size_t)NN * DOUT * 2);
  f16*   z_a    = (f16*)carve((size_t)NN * DOUT * 2);
  f16*   z_b    = (f16*)carve((size_t)NN * DOUT * 2);
  if (off > ws_size) return; // ~80 MB needed

  detect_i64<<<1, 64, 0, stream>>>(ei, flag);
  zero_cnt<<<(NN + 255) / 256, 256, 0, stream>>>(cnt);
  count_deg<<<(NE / 4 + 255) / 256, 256, 0, stream>>>(ei, flag, cnt, rank);
  scan1<<<(NN + 1023) / 1024, 1024, 0, stream>>>(cnt, rs, bsum);
  scan2<<<1, 64, 0, stream>>>(bsum, (NN + 1023) / 1024);
  scan3_and_dis<<<(NN + 255) / 256, 256, 0, stream>>>(rs, bsum, cnt, dis);
  fill_csr<<<(NE / 4 + 255) / 256, 256, 0, stream>>>(ei, flag, dis, rs, rank, recs);

  cvt_w1<<<64, 256, 0, stream>>>(W1, W1p);
  cvt_w2<<<8, 256, 0, stream>>>(W2, W2p);
  mlp_mfma<<<(NN + 63) / 64, 256, 0, stream>>>(x, W1p, b1, W2p, b2, temp, h_buf, z_a);

  const f16* zc = z_a;
  f16* zn = z_b;
  for (int k = KPROP - 1; k >= 0; k--) {
    prop_horner<<<(NN + 3) / 4, 256, 0, stream>>>(zc, zn, h_buf, out, rs, cnt,
                                                  recs, dis, temp, k, k == 0);
    const f16* t2 = zn;
    zn = (f16*)zc;
    zc = t2;
  }
}

// Round 17
// 906.837 us; speedup vs baseline: 1.3380x; 1.1066x over previous
//
#include <hip/hip_runtime.h>

#define NN 100000
#define NE 3200000
#define DIN 512
#define DHID 256
#define DOUT 64
#define KPROP 10

typedef _Float16 f16;
typedef _Float16 f16x8 __attribute__((ext_vector_type(8)));
typedef _Float16 f16x4 __attribute__((ext_vector_type(4)));
typedef float f32x4 __attribute__((ext_vector_type(4)));

// ---------------- edge-index layout probe (wave-parallel) ----------------
__global__ void detect_i64(const int* __restrict__ ei, int* __restrict__ flag) {
  int lane = threadIdx.x;
  int ok = 1;
  for (int i = lane; i < 512; i += 64)
    if (ei[2 * i + 1] != 0) ok = 0;
  ok = __all(ok);
  if (lane == 0) *flag = ok;
}

__global__ void zero_cnt(int* __restrict__ cnt) {
  int g = blockIdx.x * blockDim.x + threadIdx.x;
  if (g < NN) cnt[g] = 0;
}

// ---------------- degree count + per-edge rank (r12 measured-best) -------
// 3.2M global returning atomics ~147us: r8 routing / r11 NT / r13 coloring /
// r14 tile-LDS all failed to beat it — atomics execute at the memory-side
// coherence point; locality tricks don't apply. Measured floor.
__global__ void count_deg(const int* __restrict__ ei, const int* __restrict__ flag,
                          int* __restrict__ cnt, int* __restrict__ rank) {
  int g = blockIdx.x * blockDim.x + threadIdx.x;
  int e0 = g * 4;
  if (e0 >= NE) return;
  int is64 = *flag;
  int d0, d1, d2, d3;
  if (is64) {
    int4 a = *(const int4*)&ei[2 * (size_t)NE + 2 * (size_t)e0];
    int4 b = *(const int4*)&ei[2 * (size_t)NE + 2 * (size_t)e0 + 4];
    d0 = a.x; d1 = a.z; d2 = b.x; d3 = b.z;
  } else {
    int4 a = *(const int4*)&ei[(size_t)NE + e0];
    d0 = a.x; d1 = a.y; d2 = a.z; d3 = a.w;
  }
  int4 rk;
  rk.x = atomicAdd(&cnt[d0], 1);
  rk.y = atomicAdd(&cnt[d1], 1);
  rk.z = atomicAdd(&cnt[d2], 1);
  rk.w = atomicAdd(&cnt[d3], 1);
  *(int4*)&rank[e0] = rk;
}

// ---------------- exclusive scan over cnt ----------------
__global__ void scan1(const int* __restrict__ cnt, int* __restrict__ rs,
                      int* __restrict__ bsum) {
  __shared__ int tmp[1024];
  int t = threadIdx.x;
  int g = blockIdx.x * 1024 + t;
  int v = (g < NN) ? cnt[g] : 0;
  tmp[t] = v;
  __syncthreads();
  for (int off = 1; off < 1024; off <<= 1) {
    int y = (t >= off) ? tmp[t - off] : 0;
    __syncthreads();
    tmp[t] += y;
    __syncthreads();
  }
  if (g < NN) rs[g] = tmp[t] - v;           // exclusive
  if (t == 1023) bsum[blockIdx.x] = tmp[t]; // block total
}

__global__ void scan2(int* __restrict__ bsum, int nb) {
  if (blockIdx.x == 0 && threadIdx.x == 0) {
    int s = 0;
    for (int i = 0; i < nb; i++) { int v = bsum[i]; bsum[i] = s; s += v; }
  }
}

__global__ void scan3_and_dis(int* __restrict__ rs, const int* __restrict__ bsum,
                              const int* __restrict__ cnt, float* __restrict__ dis) {
  int g = blockIdx.x * blockDim.x + threadIdx.x;
  if (g < NN) {
    rs[g] = rs[g] + bsum[g >> 10];
    dis[g] = rsqrtf((float)(cnt[g] + 1)); // +1 self-loop
  }
}

// ---------------- CSR fill: col-only records (scaled-z removes norms) -----
// Atomic-free via precomputed ranks; 4B/edge payload (was 8B).
__global__ void fill_csr(const int* __restrict__ ei, const int* __restrict__ flag,
                         const int* __restrict__ rs, const int* __restrict__ rank,
                         int* __restrict__ col) {
  int g = blockIdx.x * blockDim.x + threadIdx.x;
  int e0 = g * 4;
  if (e0 >= NE) return;
  int is64 = *flag;
  int s[4], d[4];
  if (is64) {
    int4 a = *(const int4*)&ei[2 * (size_t)NE + 2 * (size_t)e0];
    int4 b = *(const int4*)&ei[2 * (size_t)NE + 2 * (size_t)e0 + 4];
    d[0] = a.x; d[1] = a.z; d[2] = b.x; d[3] = b.z;
    int4 c = *(const int4*)&ei[2 * (size_t)e0];
    int4 e = *(const int4*)&ei[2 * (size_t)e0 + 4];
    s[0] = c.x; s[1] = c.z; s[2] = e.x; s[3] = e.z;
  } else {
    int4 a = *(const int4*)&ei[(size_t)NE + e0];
    d[0] = a.x; d[1] = a.y; d[2] = a.z; d[3] = a.w;
    int4 c = *(const int4*)&ei[e0];
    s[0] = c.x; s[1] = c.y; s[2] = c.z; s[3] = c.w;
  }
  int4 rk = *(const int4*)&rank[e0];
  int rka[4] = { rk.x, rk.y, rk.z, rk.w };
  #pragma unroll
  for (int j = 0; j < 4; j++)
    col[rs[d[j]] + rka[j]] = s[j];
}

// ---------------- weight transpose + fp16 convert (r13 measured-best) ----
__global__ void cvt_weights(const float* __restrict__ W1, const float* __restrict__ W2,
                            f16* __restrict__ W1t, f16* __restrict__ W2t) {
  int g = blockIdx.x * 256 + threadIdx.x;
  if (g < DIN * DHID) {
    int k = g >> 8, n = g & 255;
    W1t[(size_t)n * DIN + k] = (f16)W1[g];
  }
  if (g < DHID * DOUT) {
    int k = g >> 6, n = g & 63;
    W2t[(size_t)n * DHID + k] = (f16)W2[g];
  }
}

// ---------------- fused MLP via f16 MFMA (r13 measured-best form) --------
// Epilogue: h = mlp(x); zs = dis * temp[K] * h  (scaled-z Horner seed).
__global__ __launch_bounds__(256) void mlp_mfma(
    const float* __restrict__ x, const f16* __restrict__ W1t,
    const float* __restrict__ b1, const f16* __restrict__ W2t,
    const float* __restrict__ b2, const float* __restrict__ temp,
    const float* __restrict__ dis, f16* __restrict__ h, f16* __restrict__ zs)
{
  __shared__ __align__(16) char smraw[2 * 64 * 136 * 2]; // 34816 B
  f16* xsb = (f16*)smraw;          // xs[buf][row][136]
  f16* h1s = (f16*)smraw;          // h1s[row][264] (aliased; disjoint lifetime)
  int t = threadIdx.x;
  int lane = t & 63;
  int w = t >> 6;
  int n0 = blockIdx.x * 64;
  int r15 = lane & 15;
  int g4 = lane >> 4;
  int nbase = w * 64;
  int srow = t >> 5, sc4 = t & 31;

  f32x4 acc[4][4];
  #pragma unroll
  for (int nt = 0; nt < 4; nt++) {
    float bv = b1[nbase + nt * 16 + r15];
    #pragma unroll
    for (int mt = 0; mt < 4; mt++) acc[mt][nt] = (f32x4){bv, bv, bv, bv};
  }

  float4 ld[8];
  #pragma unroll
  for (int it = 0; it < 8; it++) {
    int row = srow + it * 8;
    int gr = n0 + row;
    ld[it] = (gr < NN) ? *(const float4*)&x[(size_t)gr * DIN + sc4 * 4]
                       : make_float4(0.f, 0.f, 0.f, 0.f);
  }
  #pragma unroll
  for (int it = 0; it < 8; it++) {
    int row = srow + it * 8;
    f16x4 hv = { (f16)ld[it].x, (f16)ld[it].y, (f16)ld[it].z, (f16)ld[it].w };
    *(f16x4*)&xsb[row * 136 + sc4 * 4] = hv;
  }
  __syncthreads();

  for (int c = 0; c < 4; c++) {
    int cur = c & 1;
    if (c < 3) {  // prefetch next chunk (latency hides under compute)
      #pragma unroll
      for (int it = 0; it < 8; it++) {
        int row = srow + it * 8;
        int gr = n0 + row;
        ld[it] = (gr < NN)
            ? *(const float4*)&x[(size_t)gr * DIN + (c + 1) * 128 + sc4 * 4]
            : make_float4(0.f, 0.f, 0.f, 0.f);
      }
    }
    int k0 = c * 128;
    const f16* xs = xsb + cur * 8704;
    #pragma unroll
    for (int ks = 0; ks < 4; ks++) {
      int kk = ks * 32 + g4 * 8;
      f16x8 a[4], b[4];
      #pragma unroll
      for (int mt = 0; mt < 4; mt++)
        a[mt] = *(const f16x8*)&xs[(mt * 16 + r15) * 136 + kk];
      #pragma unroll
      for (int nt = 0; nt < 4; nt++)
        b[nt] = *(const f16x8*)&W1t[(size_t)(nbase + nt * 16 + r15) * DIN + k0 + kk];
      #pragma unroll
      for (int mt = 0; mt < 4; mt++)
        #pragma unroll
        for (int nt = 0; nt < 4; nt++)
          acc[mt][nt] = __builtin_amdgcn_mfma_f32_16x16x32_f16(a[mt], b[nt], acc[mt][nt], 0, 0, 0);
    }
    if (c < 3) {
      #pragma unroll
      for (int it = 0; it < 8; it++) {
        int row = srow + it * 8;
        f16x4 hv = { (f16)ld[it].x, (f16)ld[it].y, (f16)ld[it].z, (f16)ld[it].w };
        *(f16x4*)&xsb[(cur ^ 1) * 8704 + row * 136 + sc4 * 4] = hv;
      }
    }
    __syncthreads();
  }

  // relu -> h1s (D layout: col = lane&15, row = g4*4+reg [m89-verified])
  #pragma unroll
  for (int mt = 0; mt < 4; mt++)
    #pragma unroll
    for (int nt = 0; nt < 4; nt++)
      #pragma unroll
      for (int r = 0; r < 4; r++) {
        float v = fmaxf(acc[mt][nt][r], 0.f);
        h1s[(mt * 16 + g4 * 4 + r) * 264 + nbase + nt * 16 + r15] = (f16)v;
      }
  __syncthreads();

  // GEMM2: wave w -> rows w*16..w*16+15, cols 0..63
  f32x4 acc2[4];
  #pragma unroll
  for (int nt = 0; nt < 4; nt++) {
    float bv = b2[nt * 16 + r15];
    acc2[nt] = (f32x4){bv, bv, bv, bv};
  }
  #pragma unroll
  for (int ks = 0; ks < 8; ks++) {
    int kk = ks * 32 + g4 * 8;
    f16x8 a2 = *(const f16x8*)&h1s[(w * 16 + r15) * 264 + kk];
    #pragma unroll
    for (int nt = 0; nt < 4; nt++) {
      f16x8 bf = *(const f16x8*)&W2t[(size_t)(nt * 16 + r15) * DHID + kk];
      acc2[nt] = __builtin_amdgcn_mfma_f32_16x16x32_f16(a2, bf, acc2[nt], 0, 0, 0);
    }
  }
  float tK = temp[KPROP];
  #pragma unroll
  for (int r = 0; r < 4; r++) {
    int node = n0 + w * 16 + g4 * 4 + r;
    if (node < NN) {
      float dv = dis[node] * tK;
      #pragma unroll
      for (int nt = 0; nt < 4; nt++) {
        int colv = nt * 16 + r15;
        float v = acc2[nt][r];
        h[(size_t)node * DOUT + colv] = (f16)v;
        zs[(size_t)node * DOUT + colv] = (f16)(dv * v);
      }
    }
  }
}

// ---------------- scaled-z Horner prop ----------------
// zs = dis * z. (A_hat z)[d] = dis[d]*(sum_{s in N(d)} zs[s] + zs[d]) —
// UNWEIGHTED gather-sum, no per-edge norm, col-only 4B records.
// z_new = temp[k]*h + dis*(sum + zs_self); zs_new = dis*z_new.
// r8/r12 lane layout: q=lane>>3 edge slot, s8=lane&7 feature octet,
// butterfly xor 8/16/32.
__global__ __launch_bounds__(256) void prop_horner(
    const f16* __restrict__ zs, f16* __restrict__ zsn, const f16* __restrict__ h,
    float* __restrict__ out, const int* __restrict__ rs, const int* __restrict__ cnt,
    const int* __restrict__ col, const float* __restrict__ dis,
    const float* __restrict__ temp, int kidx, int final_step)
{
  int w = blockIdx.x * 4 + (threadIdx.x >> 6);
  int lane = threadIdx.x & 63;
  if (w >= NN) return;
  int q = lane >> 3;
  int s8 = lane & 7;

  // hoisted per-node loads (broadcast across q groups)
  float dd = dis[w];
  float gk = temp[kidx];
  f16x8 zself = *(const f16x8*)&zs[(size_t)w * DOUT + s8 * 8];
  f16x8 hs = *(const f16x8*)&h[(size_t)w * DOUT + s8 * 8];

  float acc[8];
  #pragma unroll
  for (int f = 0; f < 8; f++) acc[f] = 0.f;

  int beg = rs[w], n = cnt[w];
  const int* cp = col + beg;

  int e = 0;
  for (; e + 32 <= n; e += 32) {
    int c0 = cp[e + q];
    int c1 = cp[e + 8 + q];
    int c2 = cp[e + 16 + q];
    int c3 = cp[e + 24 + q];
    f16x8 g0 = *(const f16x8*)&zs[(size_t)c0 * DOUT + s8 * 8];
    f16x8 g1 = *(const f16x8*)&zs[(size_t)c1 * DOUT + s8 * 8];
    f16x8 g2 = *(const f16x8*)&zs[(size_t)c2 * DOUT + s8 * 8];
    f16x8 g3 = *(const f16x8*)&zs[(size_t)c3 * DOUT + s8 * 8];
    #pragma unroll
    for (int f = 0; f < 8; f++) acc[f] += (float)g0[f];
    #pragma unroll
    for (int f = 0; f < 8; f++) acc[f] += (float)g1[f];
    #pragma unroll
    for (int f = 0; f < 8; f++) acc[f] += (float)g2[f];
    #pragma unroll
    for (int f = 0; f < 8; f++) acc[f] += (float)g3[f];
  }
  for (; e + 8 <= n; e += 8) {
    int c0 = cp[e + q];
    f16x8 g0 = *(const f16x8*)&zs[(size_t)c0 * DOUT + s8 * 8];
    #pragma unroll
    for (int f = 0; f < 8; f++) acc[f] += (float)g0[f];
  }
  if (e < n) {
    int rem = n - e;
    int qq = q < rem ? q : rem - 1;   // clamp; invalid slots masked to 0
    int c0 = cp[e + qq];
    f16x8 g0 = *(const f16x8*)&zs[(size_t)c0 * DOUT + s8 * 8];
    float m = (q < rem) ? 1.f : 0.f;
    #pragma unroll
    for (int f = 0; f < 8; f++) acc[f] = fmaf(m, (float)g0[f], acc[f]);
  }

  #pragma unroll
  for (int f = 0; f < 8; f++) {
    acc[f] += __shfl_xor(acc[f], 8);
    acc[f] += __shfl_xor(acc[f], 16);
    acc[f] += __shfl_xor(acc[f], 32);
  }

  if (q == 0) {
    float zv[8];
    #pragma unroll
    for (int f = 0; f < 8; f++)
      zv[f] = gk * (float)hs[f] + dd * (acc[f] + (float)zself[f]);
    if (final_step) {
      float4 o0 = { zv[0], zv[1], zv[2], zv[3] };
      float4 o1 = { zv[4], zv[5], zv[6], zv[7] };
      *(float4*)&out[(size_t)w * DOUT + s8 * 8] = o0;
      *(float4*)&out[(size_t)w * DOUT + s8 * 8 + 4] = o1;
    } else {
      f16x8 o;
      #pragma unroll
      for (int f = 0; f < 8; f++) o[f] = (f16)(dd * zv[f]);
      *(f16x8*)&zsn[(size_t)w * DOUT + s8 * 8] = o;
    }
  }
}

// ---------------- launch ----------------
extern "C" void kernel_launch(void* const* d_in, const int* in_sizes, int n_in,
                              void* d_out, int out_size, void* d_ws, size_t ws_size,
                              hipStream_t stream) {
  const float* x    = (const float*)d_in[0];
  const int*   ei   = (const int*)d_in[1];
  const float* W1   = (const float*)d_in[2];
  const float* b1   = (const float*)d_in[3];
  const float* W2   = (const float*)d_in[4];
  const float* b2   = (const float*)d_in[5];
  const float* temp = (const float*)d_in[6];
  float* out = (float*)d_out;

  char* wsb = (char*)d_ws;
  size_t off = 0;
  auto carve = [&](size_t bytes) -> void* {
    void* p = wsb + off;
    off = (off + bytes + 255) & ~(size_t)255;
    return p;
  };
  int*   cnt    = (int*)carve((size_t)NN * 4);
  int*   rs     = (int*)carve((size_t)NN * 4);
  int*   bsum   = (int*)carve(128 * 4);
  int*   flag   = (int*)carve(256);
  float* dis    = (float*)carve((size_t)NN * 4);
  int*   rank   = (int*)carve((size_t)NE * 4);   // 12.8 MB
  int*   colA   = (int*)carve((size_t)NE * 4);   // 12.8 MB
  f16*   W1t    = (f16*)carve((size_t)DHID * DIN * 2);
  f16*   W2t    = (f16*)carve((size_t)DOUT * DHID * 2);
  f16*   h_buf  = (f16*)carve((size_t)NN * DOUT * 2);
  f16*   zs_a   = (f16*)carve((size_t)NN * DOUT * 2);
  f16*   zs_b   = (f16*)carve((size_t)NN * DOUT * 2);
  if (off > ws_size) return; // ~66 MB needed

  detect_i64<<<1, 64, 0, stream>>>(ei, flag);
  zero_cnt<<<(NN + 255) / 256, 256, 0, stream>>>(cnt);
  count_deg<<<(NE / 4 + 255) / 256, 256, 0, stream>>>(ei, flag, cnt, rank);
  scan1<<<(NN + 1023) / 1024, 1024, 0, stream>>>(cnt, rs, bsum);
  scan2<<<1, 64, 0, stream>>>(bsum, (NN + 1023) / 1024);
  scan3_and_dis<<<(NN + 255) / 256, 256, 0, stream>>>(rs, bsum, cnt, dis);
  fill_csr<<<(NE / 4 + 255) / 256, 256, 0, stream>>>(ei, flag, rs, rank, colA);

  cvt_weights<<<(DIN * DHID + 255) / 256, 256, 0, stream>>>(W1, W2, W1t, W2t);
  mlp_mfma<<<(NN + 63) / 64, 256, 0, stream>>>(x, W1t, b1, W2t, b2, temp, dis,
                                               h_buf, zs_a);

  const f16* zc = zs_a;
  f16* zn = zs_b;
  for (int k = KPROP - 1; k >= 0; k--) {
    prop_horner<<<(NN + 3) / 4, 256, 0, stream>>>(zc, zn, h_buf, out, rs, cnt,
                                                  colA, dis, temp, k, k == 0);
    const f16* t2 = zn;
    zn = (f16*)zc;
    zc = t2;
  }
}

// Round 18
// 864.554 us; speedup vs baseline: 1.4034x; 1.0489x over previous
//
#include <hip/hip_runtime.h>

#define NN 100000
#define NE 3200000
#define DIN 512
#define DHID 256
#define DOUT 64
#define KPROP 10
#define MLP_BLKS ((NN + 63) / 64)        // 1563
#define CNT_BLKS ((NE / 4 + 255) / 256)  // 3125
#define FILL_BLKS ((NE / 4 + 255) / 256) // 3125
#define SEED_BLKS 3125                   // 100000*64/2048 f16 elems

typedef _Float16 f16;
typedef _Float16 f16x8 __attribute__((ext_vector_type(8)));
typedef _Float16 f16x4 __attribute__((ext_vector_type(4)));
typedef float f32x4 __attribute__((ext_vector_type(4)));

// ---------------- zero + edge-layout probe (fused) ----------------
__global__ void zero_detect(int* __restrict__ cnt, const int* __restrict__ ei,
                            int* __restrict__ flag) {
  int g = blockIdx.x * blockDim.x + threadIdx.x;
  if (g < NN) cnt[g] = 0;
  if (blockIdx.x == 0 && threadIdx.x < 64) {
    int lane = threadIdx.x;
    int ok = 1;
    for (int i = lane; i < 512; i += 64)
      if (ei[2 * i + 1] != 0) ok = 0;
    ok = __all(ok);
    if (lane == 0) *flag = ok;
  }
}

// ---------------- weight transpose + fp16 convert ----------------
__global__ void cvt_weights(const float* __restrict__ W1, const float* __restrict__ W2,
                            f16* __restrict__ W1t, f16* __restrict__ W2t) {
  int g = blockIdx.x * 256 + threadIdx.x;
  if (g < DIN * DHID) {
    int k = g >> 8, n = g & 255;
    W1t[(size_t)n * DIN + k] = (f16)W1[g];
  }
  if (g < DHID * DOUT) {
    int k = g >> 6, n = g & 63;
    W2t[(size_t)n * DHID + k] = (f16)W2[g];
  }
}

// ---------------- FUSED: mlp (blocks 0..1562) + count_deg (rest) ---------
// count_deg is atomic-unit-bound (VALU 0.25%, HBM 10%); mlp is latency-bound
// (all pipes <12%). Disjoint resources -> co-resident blocks overlap what
// same-stream serial launches could not (286us sequential).
__global__ __launch_bounds__(256) void count_mlp(
    const int* __restrict__ ei, const int* __restrict__ flag,
    int* __restrict__ cnt, int* __restrict__ rank,
    const float* __restrict__ x, const f16* __restrict__ W1t,
    const float* __restrict__ b1, const f16* __restrict__ W2t,
    const float* __restrict__ b2, f16* __restrict__ h)
{
  __shared__ __align__(16) char smraw[2 * 64 * 136 * 2]; // 34816 B
  if (blockIdx.x >= MLP_BLKS) {
    // ---- count_deg body (r12 measured-best: rank = returning atomic) ----
    int g = (blockIdx.x - MLP_BLKS) * 256 + threadIdx.x;
    int e0 = g * 4;
    if (e0 >= NE) return;
    int is64 = *flag;
    int d0, d1, d2, d3;
    if (is64) {
      int4 a = *(const int4*)&ei[2 * (size_t)NE + 2 * (size_t)e0];
      int4 b = *(const int4*)&ei[2 * (size_t)NE + 2 * (size_t)e0 + 4];
      d0 = a.x; d1 = a.z; d2 = b.x; d3 = b.z;
    } else {
      int4 a = *(const int4*)&ei[(size_t)NE + e0];
      d0 = a.x; d1 = a.y; d2 = a.z; d3 = a.w;
    }
    int4 rk;
    rk.x = atomicAdd(&cnt[d0], 1);
    rk.y = atomicAdd(&cnt[d1], 1);
    rk.z = atomicAdd(&cnt[d2], 1);
    rk.w = atomicAdd(&cnt[d3], 1);
    *(int4*)&rank[e0] = rk;
    return;
  }
  // ---- mlp body (r13 measured-best form; writes h only) ----
  f16* xsb = (f16*)smraw;          // xs[buf][row][136]
  f16* h1s = (f16*)smraw;          // h1s[row][264] (aliased; disjoint lifetime)
  int t = threadIdx.x;
  int lane = t & 63;
  int w = t >> 6;
  int n0 = blockIdx.x * 64;
  int r15 = lane & 15;
  int g4 = lane >> 4;
  int nbase = w * 64;
  int srow = t >> 5, sc4 = t & 31;

  f32x4 acc[4][4];
  #pragma unroll
  for (int nt = 0; nt < 4; nt++) {
    float bv = b1[nbase + nt * 16 + r15];
    #pragma unroll
    for (int mt = 0; mt < 4; mt++) acc[mt][nt] = (f32x4){bv, bv, bv, bv};
  }

  float4 ld[8];
  #pragma unroll
  for (int it = 0; it < 8; it++) {
    int row = srow + it * 8;
    int gr = n0 + row;
    ld[it] = (gr < NN) ? *(const float4*)&x[(size_t)gr * DIN + sc4 * 4]
                       : make_float4(0.f, 0.f, 0.f, 0.f);
  }
  #pragma unroll
  for (int it = 0; it < 8; it++) {
    int row = srow + it * 8;
    f16x4 hv = { (f16)ld[it].x, (f16)ld[it].y, (f16)ld[it].z, (f16)ld[it].w };
    *(f16x4*)&xsb[row * 136 + sc4 * 4] = hv;
  }
  __syncthreads();

  for (int c = 0; c < 4; c++) {
    int cur = c & 1;
    if (c < 3) {  // prefetch next chunk (latency hides under compute)
      #pragma unroll
      for (int it = 0; it < 8; it++) {
        int row = srow + it * 8;
        int gr = n0 + row;
        ld[it] = (gr < NN)
            ? *(const float4*)&x[(size_t)gr * DIN + (c + 1) * 128 + sc4 * 4]
            : make_float4(0.f, 0.f, 0.f, 0.f);
      }
    }
    int k0 = c * 128;
    const f16* xs = xsb + cur * 8704;
    #pragma unroll
    for (int ks = 0; ks < 4; ks++) {
      int kk = ks * 32 + g4 * 8;
      f16x8 a[4], b[4];
      #pragma unroll
      for (int mt = 0; mt < 4; mt++)
        a[mt] = *(const f16x8*)&xs[(mt * 16 + r15) * 136 + kk];
      #pragma unroll
      for (int nt = 0; nt < 4; nt++)
        b[nt] = *(const f16x8*)&W1t[(size_t)(nbase + nt * 16 + r15) * DIN + k0 + kk];
      #pragma unroll
      for (int mt = 0; mt < 4; mt++)
        #pragma unroll
        for (int nt = 0; nt < 4; nt++)
          acc[mt][nt] = __builtin_amdgcn_mfma_f32_16x16x32_f16(a[mt], b[nt], acc[mt][nt], 0, 0, 0);
    }
    if (c < 3) {
      #pragma unroll
      for (int it = 0; it < 8; it++) {
        int row = srow + it * 8;
        f16x4 hv = { (f16)ld[it].x, (f16)ld[it].y, (f16)ld[it].z, (f16)ld[it].w };
        *(f16x4*)&xsb[(cur ^ 1) * 8704 + row * 136 + sc4 * 4] = hv;
      }
    }
    __syncthreads();
  }

  // relu -> h1s (D layout: col = lane&15, row = g4*4+reg [m89-verified])
  #pragma unroll
  for (int mt = 0; mt < 4; mt++)
    #pragma unroll
    for (int nt = 0; nt < 4; nt++)
      #pragma unroll
      for (int r = 0; r < 4; r++) {
        float v = fmaxf(acc[mt][nt][r], 0.f);
        h1s[(mt * 16 + g4 * 4 + r) * 264 + nbase + nt * 16 + r15] = (f16)v;
      }
  __syncthreads();

  f32x4 acc2[4];
  #pragma unroll
  for (int nt = 0; nt < 4; nt++) {
    float bv = b2[nt * 16 + r15];
    acc2[nt] = (f32x4){bv, bv, bv, bv};
  }
  #pragma unroll
  for (int ks = 0; ks < 8; ks++) {
    int kk = ks * 32 + g4 * 8;
    f16x8 a2 = *(const f16x8*)&h1s[(w * 16 + r15) * 264 + kk];
    #pragma unroll
    for (int nt = 0; nt < 4; nt++) {
      f16x8 bf = *(const f16x8*)&W2t[(size_t)(nt * 16 + r15) * DHID + kk];
      acc2[nt] = __builtin_amdgcn_mfma_f32_16x16x32_f16(a2, bf, acc2[nt], 0, 0, 0);
    }
  }
  #pragma unroll
  for (int nt = 0; nt < 4; nt++)
    #pragma unroll
    for (int r = 0; r < 4; r++) {
      int node = n0 + w * 16 + g4 * 4 + r;
      if (node < NN)
        h[(size_t)node * DOUT + nt * 16 + r15] = (f16)acc2[nt][r];
    }
}

// ---------------- exclusive scan over cnt ----------------
__global__ void scan1(const int* __restrict__ cnt, int* __restrict__ rs,
                      int* __restrict__ bsum) {
  __shared__ int tmp[1024];
  int t = threadIdx.x;
  int g = blockIdx.x * 1024 + t;
  int v = (g < NN) ? cnt[g] : 0;
  tmp[t] = v;
  __syncthreads();
  for (int off = 1; off < 1024; off <<= 1) {
    int y = (t >= off) ? tmp[t - off] : 0;
    __syncthreads();
    tmp[t] += y;
    __syncthreads();
  }
  if (g < NN) rs[g] = tmp[t] - v;           // exclusive
  if (t == 1023) bsum[blockIdx.x] = tmp[t]; // block total
}

// wave-parallel scan of <=128 block sums (was a ~98-iter serial
// dependent-load loop, ~15-25us)
__global__ void scan2(int* __restrict__ bsum, int nb) {
  int lane = threadIdx.x;  // 64
  int v0 = (lane < nb) ? bsum[lane] : 0;
  int v1 = (64 + lane < nb) ? bsum[64 + lane] : 0;
  int s0 = v0, s1 = v1;
  for (int off = 1; off < 64; off <<= 1) {
    int t0 = __shfl_up(s0, off);
    int t1 = __shfl_up(s1, off);
    if (lane >= off) { s0 += t0; s1 += t1; }
  }
  int tot0 = __shfl(s0, 63);
  if (lane < nb) bsum[lane] = s0 - v0;                 // exclusive
  if (64 + lane < nb) bsum[64 + lane] = tot0 + s1 - v1;
}

__global__ void scan3_and_dis(int* __restrict__ rs, const int* __restrict__ bsum,
                              const int* __restrict__ cnt, float* __restrict__ dis) {
  int g = blockIdx.x * blockDim.x + threadIdx.x;
  if (g < NN) {
    rs[g] = rs[g] + bsum[g >> 10];
    dis[g] = rsqrtf((float)(cnt[g] + 1)); // +1 self-loop
  }
}

// ---------------- FUSED: CSR fill (col-only, atomic-free) + zs seed -------
__global__ void fill_seed(const int* __restrict__ ei, const int* __restrict__ flag,
                          const int* __restrict__ rs, const int* __restrict__ rank,
                          int* __restrict__ col, const float* __restrict__ dis,
                          const float* __restrict__ temp, const f16* __restrict__ h,
                          f16* __restrict__ zs) {
  if (blockIdx.x >= FILL_BLKS) {
    // zs = dis * temp[K] * h (scaled-z Horner seed), 8 f16 per thread
    int g = (blockIdx.x - FILL_BLKS) * 256 + threadIdx.x;
    int node = g >> 3;
    if (node < NN) {
      float dv = dis[node] * temp[KPROP];
      f16x8 hv = *(const f16x8*)&h[(size_t)g * 8];
      f16x8 o;
      #pragma unroll
      for (int f = 0; f < 8; f++) o[f] = (f16)(dv * (float)hv[f]);
      *(f16x8*)&zs[(size_t)g * 8] = o;
    }
    return;
  }
  int g = blockIdx.x * blockDim.x + threadIdx.x;
  int e0 = g * 4;
  if (e0 >= NE) return;
  int is64 = *flag;
  int s[4], d[4];
  if (is64) {
    int4 a = *(const int4*)&ei[2 * (size_t)NE + 2 * (size_t)e0];
    int4 b = *(const int4*)&ei[2 * (size_t)NE + 2 * (size_t)e0 + 4];
    d[0] = a.x; d[1] = a.z; d[2] = b.x; d[3] = b.z;
    int4 c = *(const int4*)&ei[2 * (size_t)e0];
    int4 e = *(const int4*)&ei[2 * (size_t)e0 + 4];
    s[0] = c.x; s[1] = c.z; s[2] = e.x; s[3] = e.z;
  } else {
    int4 a = *(const int4*)&ei[(size_t)NE + e0];
    d[0] = a.x; d[1] = a.y; d[2] = a.z; d[3] = a.w;
    int4 c = *(const int4*)&ei[e0];
    s[0] = c.x; s[1] = c.y; s[2] = c.z; s[3] = c.w;
  }
  int4 rk = *(const int4*)&rank[e0];
  int rka[4] = { rk.x, rk.y, rk.z, rk.w };
  #pragma unroll
  for (int j = 0; j < 4; j++)
    col[rs[d[j]] + rka[j]] = s[j];
}

// ---------------- scaled-z Horner prop (r17 measured-best) ----------------
__global__ __launch_bounds__(256) void prop_horner(
    const f16* __restrict__ zs, f16* __restrict__ zsn, const f16* __restrict__ h,
    float* __restrict__ out, const int* __restrict__ rs, const int* __restrict__ cnt,
    const int* __restrict__ col, const float* __restrict__ dis,
    const float* __restrict__ temp, int kidx, int final_step)
{
  int w = blockIdx.x * 4 + (threadIdx.x >> 6);
  int lane = threadIdx.x & 63;
  if (w >= NN) return;
  int q = lane >> 3;
  int s8 = lane & 7;

  float dd = dis[w];
  float gk = temp[kidx];
  f16x8 zself = *(const f16x8*)&zs[(size_t)w * DOUT + s8 * 8];
  f16x8 hs = *(const f16x8*)&h[(size_t)w * DOUT + s8 * 8];

  float acc[8];
  #pragma unroll
  for (int f = 0; f < 8; f++) acc[f] = 0.f;

  int beg = rs[w], n = cnt[w];
  const int* cp = col + beg;

  int e = 0;
  for (; e + 32 <= n; e += 32) {
    int c0 = cp[e + q];
    int c1 = cp[e + 8 + q];
    int c2 = cp[e + 16 + q];
    int c3 = cp[e + 24 + q];
    f16x8 g0 = *(const f16x8*)&zs[(size_t)c0 * DOUT + s8 * 8];
    f16x8 g1 = *(const f16x8*)&zs[(size_t)c1 * DOUT + s8 * 8];
    f16x8 g2 = *(const f16x8*)&zs[(size_t)c2 * DOUT + s8 * 8];
    f16x8 g3 = *(const f16x8*)&zs[(size_t)c3 * DOUT + s8 * 8];
    #pragma unroll
    for (int f = 0; f < 8; f++) acc[f] += (float)g0[f];
    #pragma unroll
    for (int f = 0; f < 8; f++) acc[f] += (float)g1[f];
    #pragma unroll
    for (int f = 0; f < 8; f++) acc[f] += (float)g2[f];
    #pragma unroll
    for (int f = 0; f < 8; f++) acc[f] += (float)g3[f];
  }
  for (; e + 8 <= n; e += 8) {
    int c0 = cp[e + q];
    f16x8 g0 = *(const f16x8*)&zs[(size_t)c0 * DOUT + s8 * 8];
    #pragma unroll
    for (int f = 0; f < 8; f++) acc[f] += (float)g0[f];
  }
  if (e < n) {
    int rem = n - e;
    int qq = q < rem ? q : rem - 1;   // clamp; invalid slots masked to 0
    int c0 = cp[e + qq];
    f16x8 g0 = *(const f16x8*)&zs[(size_t)c0 * DOUT + s8 * 8];
    float m = (q < rem) ? 1.f : 0.f;
    #pragma unroll
    for (int f = 0; f < 8; f++) acc[f] = fmaf(m, (float)g0[f], acc[f]);
  }

  #pragma unroll
  for (int f = 0; f < 8; f++) {
    acc[f] += __shfl_xor(acc[f], 8);
    acc[f] += __shfl_xor(acc[f], 16);
    acc[f] += __shfl_xor(acc[f], 32);
  }

  if (q == 0) {
    float zv[8];
    #pragma unroll
    for (int f = 0; f < 8; f++)
      zv[f] = gk * (float)hs[f] + dd * (acc[f] + (float)zself[f]);
    if (final_step) {
      float4 o0 = { zv[0], zv[1], zv[2], zv[3] };
      float4 o1 = { zv[4], zv[5], zv[6], zv[7] };
      *(float4*)&out[(size_t)w * DOUT + s8 * 8] = o0;
      *(float4*)&out[(size_t)w * DOUT + s8 * 8 + 4] = o1;
    } else {
      f16x8 o;
      #pragma unroll
      for (int f = 0; f < 8; f++) o[f] = (f16)(dd * zv[f]);
      *(f16x8*)&zsn[(size_t)w * DOUT + s8 * 8] = o;
    }
  }
}

// ---------------- launch ----------------
extern "C" void kernel_launch(void* const* d_in, const int* in_sizes, int n_in,
                              void* d_out, int out_size, void* d_ws, size_t ws_size,
                              hipStream_t stream) {
  const float* x    = (const float*)d_in[0];
  const int*   ei   = (const int*)d_in[1];
  const float* W1   = (const float*)d_in[2];
  const float* b1   = (const float*)d_in[3];
  const float* W2   = (const float*)d_in[4];
  const float* b2   = (const float*)d_in[5];
  const float* temp = (const float*)d_in[6];
  float* out = (float*)d_out;

  char* wsb = (char*)d_ws;
  size_t off = 0;
  auto carve = [&](size_t bytes) -> void* {
    void* p = wsb + off;
    off = (off + bytes + 255) & ~(size_t)255;
    return p;
  };
  int*   cnt    = (int*)carve((size_t)NN * 4);
  int*   rs     = (int*)carve((size_t)NN * 4);
  int*   bsum   = (int*)carve(128 * 4);
  int*   flag   = (int*)carve(256);
  float* dis    = (float*)carve((size_t)NN * 4);
  int*   rank   = (int*)carve((size_t)NE * 4);   // 12.8 MB
  int*   colA   = (int*)carve((size_t)NE * 4);   // 12.8 MB
  f16*   W1t    = (f16*)carve((size_t)DHID * DIN * 2);
  f16*   W2t    = (f16*)carve((size_t)DOUT * DHID * 2);
  f16*   h_buf  = (f16*)carve((size_t)NN * DOUT * 2);
  f16*   zs_a   = (f16*)carve((size_t)NN * DOUT * 2);
  f16*   zs_b   = (f16*)carve((size_t)NN * DOUT * 2);
  if (off > ws_size) return; // ~66 MB needed

  zero_detect<<<(NN + 255) / 256, 256, 0, stream>>>(cnt, ei, flag);
  cvt_weights<<<(DIN * DHID + 255) / 256, 256, 0, stream>>>(W1, W2, W1t, W2t);
  count_mlp<<<MLP_BLKS + CNT_BLKS, 256, 0, stream>>>(ei, flag, cnt, rank,
                                                     x, W1t, b1, W2t, b2, h_buf);
  scan1<<<(NN + 1023) / 1024, 1024, 0, stream>>>(cnt, rs, bsum);
  scan2<<<1, 64, 0, stream>>>(bsum, (NN + 1023) / 1024);
  scan3_and_dis<<<(NN + 255) / 256, 256, 0, stream>>>(rs, bsum, cnt, dis);
  fill_seed<<<FILL_BLKS + SEED_BLKS, 256, 0, stream>>>(ei, flag, rs, rank, colA,
                                                       dis, temp, h_buf, zs_a);

  const f16* zc = zs_a;
  f16* zn = zs_b;
  for (int k = KPROP - 1; k >= 0; k--) {
    prop_horner<<<(NN + 3) / 4, 256, 0, stream>>>(zc, zn, h_buf, out, rs, cnt,
                                                  colA, dis, temp, k, k == 0);
    const f16* t2 = zn;
    zn = (f16*)zc;
    zc = t2;
  }
}